// Round 1
// baseline (1114.239 us; speedup 1.0000x reference)
//
#include <hip/hip_runtime.h>
#include <hip/hip_bf16.h>

#define T_TOKENS 16384
#define DM 512
#define DFF 2048
#define NE 8

// out layout: Y [16384*512] | router_logits [16384*8] | entropy [1]
#define RL_OFF  ((size_t)T_TOKENS * DM)            // 8388608
#define ENT_OFF (RL_OFF + (size_t)T_TOKENS * NE)   // 8519680

typedef __attribute__((ext_vector_type(8))) short short8;
typedef __attribute__((ext_vector_type(4))) float f32x4;
typedef __attribute__((ext_vector_type(4))) unsigned short u16x4;

__device__ __forceinline__ unsigned short f2bf(float f) {
    union { float f; unsigned u; } v; v.f = f;
    unsigned r = v.u + 0x7FFFu + ((v.u >> 16) & 1u);   // RNE
    return (unsigned short)(r >> 16);
}

__device__ __forceinline__ void atomAddF(float* p, float v) {
    __hip_atomic_fetch_add(p, v, __ATOMIC_RELAXED, __HIP_MEMORY_SCOPE_AGENT);
}

// ---------------- weight fp32 -> bf16 conversion ----------------
__global__ void cvt_kernel(const float* __restrict__ src, unsigned short* __restrict__ dst, size_t n4) {
    for (size_t i = blockIdx.x * (size_t)blockDim.x + threadIdx.x; i < n4;
         i += (size_t)gridDim.x * blockDim.x) {
        f32x4 v = ((const f32x4*)src)[i];
        u16x4 b;
        b.x = f2bf(v.x); b.y = f2bf(v.y); b.z = f2bf(v.z); b.w = f2bf(v.w);
        ((u16x4*)dst)[i] = b;
    }
}

// ---------------- router: one wave per token ----------------
__global__ void router_kernel(const float* __restrict__ x, const float* __restrict__ gw,
                              float* __restrict__ out, int* __restrict__ cursor,
                              int* __restrict__ toklist, float* __restrict__ wgtlist) {
    int wid  = threadIdx.x >> 6;
    int lane = threadIdx.x & 63;
    int t = blockIdx.x * 4 + wid;   // 4096 blocks * 4 waves = 16384

    const float* xr = x + (size_t)t * DM + lane * 8;
    f32x4 x0 = *(const f32x4*)xr;
    f32x4 x1 = *(const f32x4*)(xr + 4);

    float logit[NE];
#pragma unroll
    for (int e = 0; e < NE; ++e) {
        const float* g = gw + e * DM + lane * 8;
        f32x4 g0 = *(const f32x4*)g;
        f32x4 g1 = *(const f32x4*)(g + 4);
        float p = x0.x*g0.x + x0.y*g0.y + x0.z*g0.z + x0.w*g0.w
                + x1.x*g1.x + x1.y*g1.y + x1.z*g1.z + x1.w*g1.w;
#pragma unroll
        for (int off = 32; off > 0; off >>= 1) p += __shfl_xor(p, off);
        logit[e] = p;
    }
    // softmax (redundant on all lanes)
    float m = logit[0];
#pragma unroll
    for (int e = 1; e < NE; ++e) m = fmaxf(m, logit[e]);
    float pr[NE]; float s = 0.f;
#pragma unroll
    for (int e = 0; e < NE; ++e) { pr[e] = expf(logit[e] - m); s += pr[e]; }
    float inv = 1.f / s;
    float ent = 0.f;
#pragma unroll
    for (int e = 0; e < NE; ++e) { pr[e] *= inv; ent -= pr[e] * logf(fmaxf(pr[e], 1e-6f)); }
    // top-2, jax tie order (first occurrence wins)
    float p0 = -1.f, p1 = -1.f; int e0 = 0, e1 = 0;
#pragma unroll
    for (int e = 0; e < NE; ++e) {
        float p = pr[e];
        if (p > p0)      { p1 = p0; e1 = e0; p0 = p; e0 = e; }
        else if (p > p1) { p1 = p;  e1 = e; }
    }
    float wsum = p0 + p1;
    float w0 = p0 / wsum, w1 = p1 / wsum;

    if (lane == 0) {
#pragma unroll
        for (int e = 0; e < NE; ++e) out[RL_OFF + (size_t)t * NE + e] = logit[e];
        atomAddF(out + ENT_OFF, ent * (1.0f / T_TOKENS));
        int pos0 = atomicAdd(cursor + e0, 1);
        toklist[e0 * T_TOKENS + pos0] = t; wgtlist[e0 * T_TOKENS + pos0] = w0;
        int pos1 = atomicAdd(cursor + e1, 1);
        toklist[e1 * T_TOKENS + pos1] = t; wgtlist[e1 * T_TOKENS + pos1] = w1;
    }
}

// ---------------- grouped fused FFN: 128 tokens x 1 expert per block ----------------
// 512 threads = 8 waves. Waves split the N dim in both stages (no redundant B-frag reads).
// One 128x136 bf16 LDS buffer time-shared: X k-chunk during stage 1, H ff-chunk in stage 2.
// WMODE 0: bf16 weights from ws; WMODE 1: fp32 weights direct (ws too small fallback).
template <int WMODE>
__global__ __launch_bounds__(512, 2)
void ffn_kernel(const float* __restrict__ x,
                const unsigned short* __restrict__ w1b, const unsigned short* __restrict__ w2b,
                const float* __restrict__ w1f, const float* __restrict__ w2f,
                const int* __restrict__ cursor, const int* __restrict__ toklist,
                const float* __restrict__ wgtlist, float* __restrict__ out) {
    int e    = blockIdx.x & 7;     // expert == XCD (bid % 8) for L2 pinning
    int tile = blockIdx.x >> 3;
    int cnt  = cursor[e];
    int t0   = tile * 128;
    if (t0 >= cnt) return;

    __shared__ unsigned short buf[128][136];   // 34.8 KB, X-chunk / H-chunk time-shared
    __shared__ int   tIdx[128];
    __shared__ float tW[128];

    int tid = threadIdx.x;
    if (tid < 128) {
        int i = t0 + tid;
        if (i < cnt) { tIdx[tid] = toklist[e * T_TOKENS + i]; tW[tid] = wgtlist[e * T_TOKENS + i]; }
        else         { tIdx[tid] = toklist[e * T_TOKENS + t0]; tW[tid] = 0.f; }
    }
    __syncthreads();

    int wid = tid >> 6, lane = tid & 63;
    int l16 = lane & 15, lg = lane >> 4;

    f32x4 Yacc[8][4] = {};   // 128 tokens x 64 cols per wave (8 row-tiles x 4 col-tiles)

    const unsigned short* w1e = w1b + (size_t)e * DFF * DM;
    const unsigned short* w2e = w2b + (size_t)e * DM * DFF;
    const float* w1ef = w1f + (size_t)e * DFF * DM;
    const float* w2ef = w2f + (size_t)e * DM * DFF;

    for (int fc = 0; fc < 16; ++fc) {          // ff chunks of 128
        f32x4 Hacc[8] = {};                    // 128 tokens x 16 f-cols per wave
        for (int kc = 0; kc < 4; ++kc) {       // d chunks of 128
            __syncthreads();                   // prior readers of buf done
            // stage X[t0..t0+128][kc*128..+128] fp32 -> bf16 -> LDS
#pragma unroll
            for (int it = 0; it < 8; ++it) {
                int u = tid + it * 512;        // 4096 float4 units
                int row = u >> 5, c4 = u & 31;
                const float* src = x + (size_t)tIdx[row] * DM + kc * 128 + c4 * 4;
                f32x4 v = *(const f32x4*)src;
                u16x4 b;
                b.x = f2bf(v.x); b.y = f2bf(v.y); b.z = f2bf(v.z); b.w = f2bf(v.w);
                *(u16x4*)(&buf[row][c4 * 4]) = b;
            }
            __syncthreads();
            // stage 1 MFMA: H[128][f = fc*128 + wid*16 + 0..16) += X * W1^T
            int fglob = fc * 128 + wid * 16 + l16;
#pragma unroll
            for (int ks = 0; ks < 4; ++ks) {
                int kb = kc * 128 + ks * 32 + lg * 8;
                short8 B;
                if constexpr (WMODE == 0) {
                    B = *(const short8*)(w1e + (size_t)fglob * DM + kb);
                } else {
                    const float* p = w1ef + (size_t)fglob * DM + kb;
                    f32x4 b0 = *(const f32x4*)p, b1 = *(const f32x4*)(p + 4);
                    B[0]=(short)f2bf(b0.x); B[1]=(short)f2bf(b0.y); B[2]=(short)f2bf(b0.z); B[3]=(short)f2bf(b0.w);
                    B[4]=(short)f2bf(b1.x); B[5]=(short)f2bf(b1.y); B[6]=(short)f2bf(b1.z); B[7]=(short)f2bf(b1.w);
                }
#pragma unroll
                for (int rt = 0; rt < 8; ++rt) {
                    short8 A = *(const short8*)(&buf[rt * 16 + l16][ks * 32 + lg * 8]);
                    Hacc[rt] = __builtin_amdgcn_mfma_f32_16x16x32_bf16(A, B, Hacc[rt], 0, 0, 0);
                }
            }
        }
        __syncthreads();   // all X reads done; buf becomes H
        // GELU (exact erf) + write H as bf16 into buf
#pragma unroll
        for (int rt = 0; rt < 8; ++rt) {
#pragma unroll
            for (int r = 0; r < 4; ++r) {
                float h = Hacc[rt][r];
                float g = h * 0.5f * (1.0f + erff(h * 0.70710678f));
                buf[rt * 16 + lg * 4 + r][wid * 16 + l16] = f2bf(g);
            }
        }
        __syncthreads();
        // stage 2 MFMA: Y[128][g = wid*64 + 0..64) += H * W2^T  (k = f local 0..128)
#pragma unroll
        for (int ks = 0; ks < 4; ++ks) {
            short8 B[4];
#pragma unroll
            for (int gt = 0; gt < 4; ++gt) {
                int g = wid * 64 + gt * 16 + l16;
                int kf = fc * 128 + ks * 32 + lg * 8;
                if constexpr (WMODE == 0) {
                    B[gt] = *(const short8*)(w2e + (size_t)g * DFF + kf);
                } else {
                    const float* p = w2ef + (size_t)g * DFF + kf;
                    f32x4 b0 = *(const f32x4*)p, b1 = *(const f32x4*)(p + 4);
                    B[gt][0]=(short)f2bf(b0.x); B[gt][1]=(short)f2bf(b0.y); B[gt][2]=(short)f2bf(b0.z); B[gt][3]=(short)f2bf(b0.w);
                    B[gt][4]=(short)f2bf(b1.x); B[gt][5]=(short)f2bf(b1.y); B[gt][6]=(short)f2bf(b1.z); B[gt][7]=(short)f2bf(b1.w);
                }
            }
#pragma unroll
            for (int rt = 0; rt < 8; ++rt) {
                short8 A = *(const short8*)(&buf[rt * 16 + l16][ks * 32 + lg * 8]);
#pragma unroll
                for (int gt = 0; gt < 4; ++gt)
                    Yacc[rt][gt] = __builtin_amdgcn_mfma_f32_16x16x32_bf16(A, B[gt], Yacc[rt][gt], 0, 0, 0);
            }
        }
    }
    // epilogue: scale by routing weight, atomic scatter-add
#pragma unroll
    for (int rt = 0; rt < 8; ++rt) {
#pragma unroll
        for (int r = 0; r < 4; ++r) {
            int row = rt * 16 + lg * 4 + r;
            float wgt = tW[row];
            size_t t = (size_t)tIdx[row];
#pragma unroll
            for (int gt = 0; gt < 4; ++gt) {
                int g = wid * 64 + gt * 16 + l16;
                atomAddF(out + t * DM + g, Yacc[rt][gt][r] * wgt);
            }
        }
    }
}

extern "C" void kernel_launch(void* const* d_in, const int* in_sizes, int n_in,
                              void* d_out, int out_size, void* d_ws, size_t ws_size,
                              hipStream_t stream) {
    const float* x  = (const float*)d_in[0];
    const float* gw = (const float*)d_in[1];
    const float* w1 = (const float*)d_in[2];
    const float* w2 = (const float*)d_in[3];
    float* out = (float*)d_out;

    const size_t W1N = (size_t)NE * DFF * DM;   // 8388608
    const size_t W2N = (size_t)NE * DM * DFF;   // 8388608
    const size_t wbytes = (W1N + W2N) * 2;      // 32 MiB bf16 weights
    const size_t listbytes = 256 + (size_t)NE * T_TOKENS * 4 * 2;
    bool bf16w = ws_size >= wbytes + listbytes;

    unsigned short* w1b; unsigned short* w2b; int* cursor;
    if (bf16w) {
        w1b = (unsigned short*)d_ws;
        w2b = w1b + W1N;
        cursor = (int*)((char*)d_ws + wbytes);
    } else {
        w1b = nullptr; w2b = nullptr;
        cursor = (int*)d_ws;
    }
    int*   toklist = (int*)((char*)cursor + 256);
    float* wgtlist = (float*)(toklist + NE * T_TOKENS);

    hipMemsetAsync(out, 0, (size_t)out_size * sizeof(float), stream);
    hipMemsetAsync(cursor, 0, 64, stream);

    if (bf16w) {
        cvt_kernel<<<2048, 256, 0, stream>>>(w1, w1b, W1N / 4);
        cvt_kernel<<<2048, 256, 0, stream>>>(w2, w2b, W2N / 4);
    }
    router_kernel<<<T_TOKENS / 4, 256, 0, stream>>>(x, gw, out, cursor, toklist, wgtlist);

    if (bf16w)
        ffn_kernel<0><<<NE * 128, 512, 0, stream>>>(x, w1b, w2b, nullptr, nullptr,
                                                    cursor, toklist, wgtlist, out);
    else
        ffn_kernel<1><<<NE * 128, 512, 0, stream>>>(x, nullptr, nullptr, w1, w2,
                                                    cursor, toklist, wgtlist, out);
}

// Round 2
// 846.574 us; speedup vs baseline: 1.3162x; 1.3162x over previous
//
#include <hip/hip_runtime.h>
#include <hip/hip_bf16.h>
#include <math.h>

#define T_TOKENS 16384
#define DM 512
#define DFF 2048
#define NE 8
#define TOKT 64
#define FCH 512

// out layout: Y [16384*512] | router_logits [16384*8] | entropy [1]
#define RL_OFF  ((size_t)T_TOKENS * DM)
#define ENT_OFF (RL_OFF + (size_t)T_TOKENS * NE)

typedef __attribute__((ext_vector_type(8))) short short8;
typedef __attribute__((ext_vector_type(4))) float f32x4;

__device__ __forceinline__ unsigned short f2bf(float f) {
    union { float f; unsigned u; } v; v.f = f;
    unsigned r = v.u + 0x7FFFu + ((v.u >> 16) & 1u);   // RNE
    return (unsigned short)(r >> 16);
}

__device__ __forceinline__ void atomAddF(float* p, float v) {
    __hip_atomic_fetch_add(p, v, __ATOMIC_RELAXED, __HIP_MEMORY_SCOPE_AGENT);
}

// ---------------- weight fp32 -> bf16 conversion ----------------
__global__ void cvt_kernel(const float* __restrict__ src, unsigned short* __restrict__ dst, size_t n4) {
    for (size_t i = blockIdx.x * (size_t)blockDim.x + threadIdx.x; i < n4;
         i += (size_t)gridDim.x * blockDim.x) {
        f32x4 v = ((const f32x4*)src)[i];
        unsigned short b0 = f2bf(v.x), b1 = f2bf(v.y), b2 = f2bf(v.z), b3 = f2bf(v.w);
        ((unsigned long long*)dst)[i] =
            (unsigned long long)b0 | ((unsigned long long)b1 << 16) |
            ((unsigned long long)b2 << 32) | ((unsigned long long)b3 << 48);
    }
}

// ---------------- router: 1024 threads = 16 waves, 1 token per wave ----------------
__global__ __launch_bounds__(1024)
void router_kernel(const float* __restrict__ x, const float* __restrict__ gw,
                   float* __restrict__ out, int* __restrict__ cursor,
                   int* __restrict__ toklist, float* __restrict__ wgtlist,
                   float* __restrict__ entPartial) {
    __shared__ int   lcnt[NE];
    __shared__ int   lbase[NE];
    __shared__ float lent[16];
    __shared__ int   le[16][2];
    __shared__ int   lpos[16][2];
    __shared__ float lw[16][2];

    int tid = threadIdx.x;
    int wid = tid >> 6, lane = tid & 63;
    int t = blockIdx.x * 16 + wid;
    if (tid < NE) lcnt[tid] = 0;
    __syncthreads();

    const float* xr = x + (size_t)t * DM + lane * 8;
    f32x4 x0 = *(const f32x4*)xr;
    f32x4 x1 = *(const f32x4*)(xr + 4);

    float logit[NE];
#pragma unroll
    for (int e = 0; e < NE; ++e) {
        const float* g = gw + e * DM + lane * 8;
        f32x4 g0 = *(const f32x4*)g;
        f32x4 g1 = *(const f32x4*)(g + 4);
        float p = x0.x*g0.x + x0.y*g0.y + x0.z*g0.z + x0.w*g0.w
                + x1.x*g1.x + x1.y*g1.y + x1.z*g1.z + x1.w*g1.w;
#pragma unroll
        for (int off = 32; off > 0; off >>= 1) p += __shfl_xor(p, off);
        logit[e] = p;
    }
    float m = logit[0];
#pragma unroll
    for (int e = 1; e < NE; ++e) m = fmaxf(m, logit[e]);
    float pr[NE]; float s = 0.f;
#pragma unroll
    for (int e = 0; e < NE; ++e) { pr[e] = expf(logit[e] - m); s += pr[e]; }
    float inv = 1.f / s;
    float ent = 0.f;
#pragma unroll
    for (int e = 0; e < NE; ++e) { pr[e] *= inv; ent -= pr[e] * logf(fmaxf(pr[e], 1e-6f)); }
    // top-2, first occurrence wins ties (jax top_k order)
    float p0 = -1.f, p1 = -1.f; int e0 = 0, e1 = 0;
#pragma unroll
    for (int e = 0; e < NE; ++e) {
        float p = pr[e];
        if (p > p0)      { p1 = p0; e1 = e0; p0 = p; e0 = e; }
        else if (p > p1) { p1 = p;  e1 = e; }
    }
    float wsum = p0 + p1;

    if (lane == 0) {
        lent[wid] = ent;
        le[wid][0] = e0; le[wid][1] = e1;
        lw[wid][0] = p0 / wsum; lw[wid][1] = p1 / wsum;
        lpos[wid][0] = atomicAdd(&lcnt[e0], 1);
        lpos[wid][1] = atomicAdd(&lcnt[e1], 1);
    }
    // router logits: lane e writes logit[e] (static-index select, no scratch)
    float myLogit = 0.f;
#pragma unroll
    for (int e = 0; e < NE; ++e) if (lane == e) myLogit = logit[e];
    if (lane < NE) out[RL_OFF + (size_t)t * NE + lane] = myLogit;

    __syncthreads();
    if (tid < NE) lbase[tid] = atomicAdd(cursor + tid, lcnt[tid]);
    __syncthreads();
    if (tid < 16) {
        int a0 = le[tid][0], a1 = le[tid][1];
        int tt = blockIdx.x * 16 + tid;
        int q0 = lbase[a0] + lpos[tid][0];
        int q1 = lbase[a1] + lpos[tid][1];
        toklist[a0 * T_TOKENS + q0] = tt; wgtlist[a0 * T_TOKENS + q0] = lw[tid][0];
        toklist[a1 * T_TOKENS + q1] = tt; wgtlist[a1 * T_TOKENS + q1] = lw[tid][1];
    }
    if (tid == 0) {
        float sum = 0.f;
#pragma unroll
        for (int w = 0; w < 16; ++w) sum += lent[w];
        entPartial[blockIdx.x] = sum;
    }
}

__global__ void ent_reduce(const float* __restrict__ part, float* __restrict__ out) {
    __shared__ float s[16];
    int tid = threadIdx.x;
    float v = part[tid];
#pragma unroll
    for (int off = 32; off > 0; off >>= 1) v += __shfl_xor(v, off);
    if ((tid & 63) == 0) s[tid >> 6] = v;
    __syncthreads();
    if (tid == 0) {
        float tot = 0.f;
#pragma unroll
        for (int w = 0; w < 16; ++w) tot += s[w];
        out[ENT_OFF] = tot * (1.0f / T_TOKENS);
    }
}

// ---------------- weight fragment load helper ----------------
template <int WMODE>
__device__ __forceinline__ short8 ldw(const unsigned short* wb, const float* wf, size_t off) {
    if constexpr (WMODE == 0) {
        return *(const short8*)(wb + off);
    } else {
        const float* p = wf + off;
        f32x4 a = *(const f32x4*)p, b = *(const f32x4*)(p + 4);
        short8 r;
        r[0]=(short)f2bf(a.x); r[1]=(short)f2bf(a.y); r[2]=(short)f2bf(a.z); r[3]=(short)f2bf(a.w);
        r[4]=(short)f2bf(b.x); r[5]=(short)f2bf(b.y); r[6]=(short)f2bf(b.z); r[7]=(short)f2bf(b.w);
        return r;
    }
}

// ---------------- grouped fused FFN ----------------
// 64-token tile x 1 expert per block; 512 threads = 8 waves, waves split N.
// X staged ONCE into swizzled LDS (64 KiB). FCH=512 H chunk (64 KiB, swizzled).
// 4 fc iterations, 2 barriers each. Weights bf16 streamed from L2 (expert==XCD).
template <int WMODE>
__global__ __launch_bounds__(512)
void ffn_kernel(const float* __restrict__ x,
                const unsigned short* __restrict__ w1b, const unsigned short* __restrict__ w2b,
                const float* __restrict__ w1f, const float* __restrict__ w2f,
                const int* __restrict__ cursor, const int* __restrict__ toklist,
                const float* __restrict__ wgtlist, float* __restrict__ out) {
    int e    = blockIdx.x & 7;     // expert == XCD (round-robin dispatch) for L2 pinning
    int tile = blockIdx.x >> 3;
    int cnt  = cursor[e];
    int t0   = tile * TOKT;
    if (t0 >= cnt) return;

    __shared__ unsigned short Xs[TOKT * DM];    // 64 KiB, row stride 1024 B, XOR-swizzled
    __shared__ unsigned short Hs[TOKT * FCH];   // 64 KiB, same
    __shared__ int   tIdx[TOKT];
    __shared__ float tW[TOKT];

    int tid = threadIdx.x;
    if (tid < TOKT) {
        int i = t0 + tid;
        int src = (i < cnt) ? i : t0;
        tIdx[tid] = toklist[e * T_TOKENS + src];
        tW[tid]   = (i < cnt) ? wgtlist[e * T_TOKENS + i] : 0.f;
    }
    __syncthreads();

    // ---- stage X once: fp32 -> bf16 -> swizzled LDS (4096 16B units, 8/thread) ----
#pragma unroll
    for (int it = 0; it < 8; ++it) {
        int u = tid + it * 512;
        int row = u >> 6, c16 = u & 63;
        const float* src = x + (size_t)tIdx[row] * DM + c16 * 8;
        f32x4 v0 = *(const f32x4*)src;
        f32x4 v1 = *(const f32x4*)(src + 4);
        short8 b;
        b[0]=(short)f2bf(v0.x); b[1]=(short)f2bf(v0.y); b[2]=(short)f2bf(v0.z); b[3]=(short)f2bf(v0.w);
        b[4]=(short)f2bf(v1.x); b[5]=(short)f2bf(v1.y); b[6]=(short)f2bf(v1.z); b[7]=(short)f2bf(v1.w);
        *(short8*)((char*)Xs + row * 1024 + ((c16 * 16) ^ ((row & 15) << 4))) = b;
    }
    __syncthreads();

    int wid = tid >> 6, lane = tid & 63;
    int l16 = lane & 15, lg = lane >> 4;

    f32x4 Yacc[4][4] = {};
    const unsigned short* w1e = w1b + (WMODE == 0 ? (size_t)e * DFF * DM : 0);
    const unsigned short* w2e = w2b + (WMODE == 0 ? (size_t)e * DM * DFF : 0);
    const float* w1ef = w1f + (WMODE == 1 ? (size_t)e * DFF * DM : 0);
    const float* w2ef = w2f + (WMODE == 1 ? (size_t)e * DM * DFF : 0);

#pragma unroll 1
    for (int fc = 0; fc < 4; ++fc) {
        f32x4 Hacc[4][4] = {};
        // ---- stage1: H[64][FCH] slice; wave cols = wid*64 + ct*16 + l16 ----
#pragma unroll
        for (int ks = 0; ks < 16; ++ks) {
            short8 B[4];
#pragma unroll
            for (int ct = 0; ct < 4; ++ct) {
                int f = fc * FCH + wid * 64 + ct * 16 + l16;
                B[ct] = ldw<WMODE>(w1e, w1ef, (size_t)f * DM + ks * 32 + lg * 8);
            }
#pragma unroll
            for (int rt = 0; rt < 4; ++rt) {
                int row = rt * 16 + l16;
                short8 A = *(const short8*)((const char*)Xs + row * 1024 +
                                            ((ks * 64 + lg * 16) ^ ((row & 15) << 4)));
#pragma unroll
                for (int ct = 0; ct < 4; ++ct)
                    Hacc[rt][ct] = __builtin_amdgcn_mfma_f32_16x16x32_bf16(A, B[ct], Hacc[rt][ct], 0, 0, 0);
            }
        }
        __syncthreads();   // prev fc's stage2 readers done with Hs
        // ---- GELU (exact erf) -> Hs (bf16, swizzled) ----
#pragma unroll
        for (int rt = 0; rt < 4; ++rt)
#pragma unroll
        for (int ct = 0; ct < 4; ++ct)
#pragma unroll
        for (int r = 0; r < 4; ++r) {
            float h = Hacc[rt][ct][r];
            float g = 0.5f * h * (1.0f + erff(h * 0.70710678118f));
            int row = rt * 16 + lg * 4 + r;
            int colb = (wid * 64 + ct * 16 + l16) * 2;
            *(unsigned short*)((char*)Hs + row * 1024 + (colb ^ ((row & 15) << 4))) = f2bf(g);
        }
        __syncthreads();
        // ---- stage2: Y[64][512] += H_chunk * W2_chunk^T ----
#pragma unroll
        for (int ks = 0; ks < 16; ++ks) {
            short8 B[4];
#pragma unroll
            for (int ct = 0; ct < 4; ++ct) {
                int g = wid * 64 + ct * 16 + l16;
                B[ct] = ldw<WMODE>(w2e, w2ef, (size_t)g * DFF + fc * FCH + ks * 32 + lg * 8);
            }
#pragma unroll
            for (int rt = 0; rt < 4; ++rt) {
                int row = rt * 16 + l16;
                short8 A = *(const short8*)((const char*)Hs + row * 1024 +
                                            ((ks * 64 + lg * 16) ^ ((row & 15) << 4)));
#pragma unroll
                for (int ct = 0; ct < 4; ++ct)
                    Yacc[rt][ct] = __builtin_amdgcn_mfma_f32_16x16x32_bf16(A, B[ct], Yacc[rt][ct], 0, 0, 0);
            }
        }
    }
    // ---- epilogue: scale + atomic scatter-add ----
#pragma unroll
    for (int rt = 0; rt < 4; ++rt)
#pragma unroll
    for (int r = 0; r < 4; ++r) {
        int row = rt * 16 + lg * 4 + r;
        float wgt = tW[row];
        size_t t = (size_t)tIdx[row];
        float* orow = out + t * DM + wid * 64;
#pragma unroll
        for (int ct = 0; ct < 4; ++ct)
            atomAddF(orow + ct * 16 + l16, Yacc[rt][ct][r] * wgt);
    }
}

extern "C" void kernel_launch(void* const* d_in, const int* in_sizes, int n_in,
                              void* d_out, int out_size, void* d_ws, size_t ws_size,
                              hipStream_t stream) {
    const float* x  = (const float*)d_in[0];
    const float* gw = (const float*)d_in[1];
    const float* w1 = (const float*)d_in[2];
    const float* w2 = (const float*)d_in[3];
    float* out = (float*)d_out;

    const size_t W1N = (size_t)NE * DFF * DM;
    const size_t W2N = (size_t)NE * DM * DFF;
    const size_t wbytes = (W1N + W2N) * 2;                       // 32 MiB bf16 weights
    const size_t auxbytes = 256 + (size_t)NE * T_TOKENS * 4 * 2 + 4096;
    bool bf16w = ws_size >= wbytes + auxbytes;

    unsigned short* w1b; unsigned short* w2b; int* cursor;
    if (bf16w) {
        w1b = (unsigned short*)d_ws;
        w2b = w1b + W1N;
        cursor = (int*)((char*)d_ws + wbytes);
    } else {
        w1b = nullptr; w2b = nullptr;
        cursor = (int*)d_ws;
    }
    int*   toklist = (int*)((char*)cursor + 256);
    float* wgtlist = (float*)(toklist + NE * T_TOKENS);
    float* entPart = (float*)(wgtlist + NE * T_TOKENS);

    hipMemsetAsync(out, 0, (size_t)out_size * sizeof(float), stream);
    hipMemsetAsync(cursor, 0, 64, stream);

    if (bf16w) {
        cvt_kernel<<<2048, 256, 0, stream>>>(w1, w1b, W1N / 4);
        cvt_kernel<<<2048, 256, 0, stream>>>(w2, w2b, W2N / 4);
    }
    router_kernel<<<T_TOKENS / 16, 1024, 0, stream>>>(x, gw, out, cursor, toklist, wgtlist, entPart);
    ent_reduce<<<1, 1024, 0, stream>>>(entPart, out);

    if (bf16w)
        ffn_kernel<0><<<NE * 256, 512, 0, stream>>>(x, w1b, w2b, nullptr, nullptr,
                                                    cursor, toklist, wgtlist, out);
    else
        ffn_kernel<1><<<NE * 256, 512, 0, stream>>>(x, nullptr, nullptr, w1, w2,
                                                    cursor, toklist, wgtlist, out);
}

// Round 3
// 527.278 us; speedup vs baseline: 2.1132x; 1.6056x over previous
//
#include <hip/hip_runtime.h>
#include <hip/hip_bf16.h>
#include <math.h>

#define T_TOKENS 16384
#define DM 512
#define DFF 2048
#define NE 8
#define TOKT 64
#define FCH 256
#define NFC (DFF / FCH)   // 8

// out layout: Y [16384*512] | router_logits [16384*8] | entropy [1]
#define RL_OFF  ((size_t)T_TOKENS * DM)
#define ENT_OFF (RL_OFF + (size_t)T_TOKENS * NE)

typedef __attribute__((ext_vector_type(8))) short short8;
typedef __attribute__((ext_vector_type(4))) float f32x4;

__device__ __forceinline__ unsigned short f2bf(float f) {
    union { float f; unsigned u; } v; v.f = f;
    unsigned r = v.u + 0x7FFFu + ((v.u >> 16) & 1u);   // RNE
    return (unsigned short)(r >> 16);
}
__device__ __forceinline__ float bf2f(unsigned short h) {
    union { unsigned u; float f; } v; v.u = ((unsigned)h) << 16; return v.f;
}
__device__ __forceinline__ void atomAddF(float* p, float v) {
    __hip_atomic_fetch_add(p, v, __ATOMIC_RELAXED, __HIP_MEMORY_SCOPE_AGENT);
}

// ---------------- fp32 -> bf16 conversion ----------------
__global__ void cvt_kernel(const float* __restrict__ src, unsigned short* __restrict__ dst, size_t n4) {
    for (size_t i = blockIdx.x * (size_t)blockDim.x + threadIdx.x; i < n4;
         i += (size_t)gridDim.x * blockDim.x) {
        f32x4 v = ((const f32x4*)src)[i];
        unsigned short b0 = f2bf(v.x), b1 = f2bf(v.y), b2 = f2bf(v.z), b3 = f2bf(v.w);
        ((unsigned long long*)dst)[i] =
            (unsigned long long)b0 | ((unsigned long long)b1 << 16) |
            ((unsigned long long)b2 << 32) | ((unsigned long long)b3 << 48);
    }
}

// ---------------- router: 1024 threads = 16 waves, 1 token per wave ----------------
__global__ __launch_bounds__(1024)
void router_kernel(const float* __restrict__ x, const float* __restrict__ gw,
                   float* __restrict__ out, int* __restrict__ cursor,
                   int* __restrict__ slotlist, float* __restrict__ wgtlist,
                   float* __restrict__ entPartial) {
    __shared__ int   lcnt[NE];
    __shared__ int   lbase[NE];
    __shared__ float lent[16];
    __shared__ int   le[16][2];
    __shared__ int   lpos[16][2];
    __shared__ float lw[16][2];

    int tid = threadIdx.x;
    int wid = tid >> 6, lane = tid & 63;
    int t = blockIdx.x * 16 + wid;
    if (tid < NE) lcnt[tid] = 0;
    __syncthreads();

    const float* xr = x + (size_t)t * DM + lane * 8;
    f32x4 x0 = *(const f32x4*)xr;
    f32x4 x1 = *(const f32x4*)(xr + 4);

    float logit[NE];
#pragma unroll
    for (int e = 0; e < NE; ++e) {
        const float* g = gw + e * DM + lane * 8;
        f32x4 g0 = *(const f32x4*)g;
        f32x4 g1 = *(const f32x4*)(g + 4);
        float p = x0.x*g0.x + x0.y*g0.y + x0.z*g0.z + x0.w*g0.w
                + x1.x*g1.x + x1.y*g1.y + x1.z*g1.z + x1.w*g1.w;
#pragma unroll
        for (int off = 32; off > 0; off >>= 1) p += __shfl_xor(p, off);
        logit[e] = p;
    }
    float m = logit[0];
#pragma unroll
    for (int e = 1; e < NE; ++e) m = fmaxf(m, logit[e]);
    float pr[NE]; float s = 0.f;
#pragma unroll
    for (int e = 0; e < NE; ++e) { pr[e] = expf(logit[e] - m); s += pr[e]; }
    float inv = 1.f / s;
    float ent = 0.f;
#pragma unroll
    for (int e = 0; e < NE; ++e) { pr[e] *= inv; ent -= pr[e] * logf(fmaxf(pr[e], 1e-6f)); }
    // top-2, first occurrence wins ties (jax top_k order)
    float p0 = -1.f, p1 = -1.f; int e0 = 0, e1 = 0;
#pragma unroll
    for (int e = 0; e < NE; ++e) {
        float p = pr[e];
        if (p > p0)      { p1 = p0; e1 = e0; p0 = p; e0 = e; }
        else if (p > p1) { p1 = p;  e1 = e; }
    }
    float wsum = p0 + p1;

    if (lane == 0) {
        lent[wid] = ent;
        le[wid][0] = e0; le[wid][1] = e1;
        lw[wid][0] = p0 / wsum; lw[wid][1] = p1 / wsum;
        lpos[wid][0] = atomicAdd(&lcnt[e0], 1);
        lpos[wid][1] = atomicAdd(&lcnt[e1], 1);
    }
    float myLogit = 0.f;
#pragma unroll
    for (int e = 0; e < NE; ++e) if (lane == e) myLogit = logit[e];
    if (lane < NE) out[RL_OFF + (size_t)t * NE + lane] = myLogit;

    __syncthreads();
    if (tid < NE) lbase[tid] = atomicAdd(cursor + tid, lcnt[tid]);
    __syncthreads();
    if (tid < 16) {
        int a0 = le[tid][0], a1 = le[tid][1];
        int tt = blockIdx.x * 16 + tid;
        int q0 = lbase[a0] + lpos[tid][0];
        int q1 = lbase[a1] + lpos[tid][1];
        slotlist[a0 * T_TOKENS + q0] = tt * 2;     wgtlist[a0 * T_TOKENS + q0] = lw[tid][0];
        slotlist[a1 * T_TOKENS + q1] = tt * 2 + 1; wgtlist[a1 * T_TOKENS + q1] = lw[tid][1];
    }
    if (tid == 0) {
        float sum = 0.f;
#pragma unroll
        for (int w = 0; w < 16; ++w) sum += lent[w];
        entPartial[blockIdx.x] = sum;
    }
}

__global__ void ent_reduce(const float* __restrict__ part, float* __restrict__ out) {
    __shared__ float s[16];
    int tid = threadIdx.x;
    float v = part[tid];
#pragma unroll
    for (int off = 32; off > 0; off >>= 1) v += __shfl_xor(v, off);
    if ((tid & 63) == 0) s[tid >> 6] = v;
    __syncthreads();
    if (tid == 0) {
        float tot = 0.f;
#pragma unroll
        for (int w = 0; w < 16; ++w) tot += s[w];
        out[ENT_OFF] = tot * (1.0f / T_TOKENS);
    }
}

// ---------------- grouped fused FFN ----------------
// 64-token tile x 1 expert per block, 512 threads = 8 waves, grid NE*64 (2 rounds/CU).
// X fully LDS-resident (64 KB, XOR-swizzled), Hs 32 KB -> 96 KB LDS, 1 block/CU.
// Stage-1 K-loop: pure {global B-loads + ds_read A + MFMA}, no barriers inside.
// XB: 1 = bf16 X source, 0 = fp32 X source. SLOT: 1 = Ybuf store, 0 = atomic out.
template <int XB, int SLOT>
__global__ __launch_bounds__(512, 2)
void ffn_kernel(const float* __restrict__ x, const unsigned short* __restrict__ xb,
                const unsigned short* __restrict__ w1b, const unsigned short* __restrict__ w2b,
                const int* __restrict__ cursor, const int* __restrict__ slotlist,
                const float* __restrict__ wgtlist,
                unsigned short* __restrict__ ybuf, float* __restrict__ out) {
    __shared__ unsigned short Xs[TOKT * DM];    // 64 KB, row stride 1024 B, swizzled
    __shared__ unsigned short Hs[TOKT * FCH];   // 32 KB, row stride 512 B, swizzled

    int e   = blockIdx.x & 7;                   // expert == XCD for L2 pinning
    int cnt = cursor[e];
    int tid = threadIdx.x;
    int wid = tid >> 6, lane = tid & 63;
    int l16 = lane & 15, lg = lane >> 4;

    const unsigned short* w1e = w1b + (size_t)e * DFF * DM;
    const unsigned short* w2e = w2b + (size_t)e * DM * DFF;
    const int*   sl = slotlist + e * T_TOKENS;
    const float* wl = wgtlist  + e * T_TOKENS;

    int step = (gridDim.x >> 3) * TOKT;
#pragma unroll 1
    for (int t0 = (blockIdx.x >> 3) * TOKT; t0 < cnt; t0 += step) {
        // ---- stage X once: 4096 x 16B units, 8 per thread ----
#pragma unroll
        for (int it = 0; it < 8; ++it) {
            int u = tid + it * 512;
            int row = u >> 6, c16 = u & 63;
            int idx = t0 + row;
            int entry = sl[(idx < cnt) ? idx : t0];
            int t = entry >> 1;
            short8 v;
            if constexpr (XB == 1) {
                v = *(const short8*)(xb + (size_t)t * DM + c16 * 8);
            } else {
                const float* src = x + (size_t)t * DM + c16 * 8;
                f32x4 a = *(const f32x4*)src, b = *(const f32x4*)(src + 4);
                v[0]=(short)f2bf(a.x); v[1]=(short)f2bf(a.y); v[2]=(short)f2bf(a.z); v[3]=(short)f2bf(a.w);
                v[4]=(short)f2bf(b.x); v[5]=(short)f2bf(b.y); v[6]=(short)f2bf(b.z); v[7]=(short)f2bf(b.w);
            }
            *(short8*)((char*)Xs + row * 1024 + ((c16 << 4) ^ ((row & 7) << 4))) = v;
        }
        __syncthreads();

        f32x4 Yacc[4][4] = {};   // [rt][ct] : 64 tokens x 64 g-cols per wave

#pragma unroll 1
        for (int fc = 0; fc < NFC; ++fc) {
            // ---- stage1: Hacc[rt][ct1], wave f-block = wid*32 ----
            f32x4 Hacc[4][2] = {};
            const unsigned short* w1p0 = w1e + (size_t)(fc * FCH + wid * 32 + l16) * DM + lg * 8;
            const unsigned short* w1p1 = w1p0 + (size_t)16 * DM;
#pragma unroll
            for (int ks = 0; ks < 16; ++ks) {
                short8 B0 = *(const short8*)(w1p0 + ks * 32);
                short8 B1 = *(const short8*)(w1p1 + ks * 32);
#pragma unroll
                for (int rt = 0; rt < 4; ++rt) {
                    int row = rt * 16 + l16;
                    short8 A = *(const short8*)((const char*)Xs + row * 1024 +
                                ((ks * 64 + lg * 16) ^ ((row & 7) << 4)));
                    Hacc[rt][0] = __builtin_amdgcn_mfma_f32_16x16x32_bf16(A, B0, Hacc[rt][0], 0, 0, 0);
                    Hacc[rt][1] = __builtin_amdgcn_mfma_f32_16x16x32_bf16(A, B1, Hacc[rt][1], 0, 0, 0);
                }
            }
            __syncthreads();   // all waves done reading Hs (previous fc's stage2)
            // ---- GELU (exact erf) -> Hs bf16 swizzled ----
#pragma unroll
            for (int rt = 0; rt < 4; ++rt)
#pragma unroll
            for (int ct = 0; ct < 2; ++ct)
#pragma unroll
            for (int r = 0; r < 4; ++r) {
                float h = Hacc[rt][ct][r];
                float g = 0.5f * h * (1.0f + erff(h * 0.70710678118f));
                int row = rt * 16 + lg * 4 + r;
                int colb = (wid * 32 + ct * 16 + l16) * 2;
                *(unsigned short*)((char*)Hs + row * 512 + (colb ^ ((row & 7) << 4))) = f2bf(g);
            }
            __syncthreads();
            // ---- stage2: Y += H_chunk * W2_chunk^T, wave g-block = wid*64 ----
            const unsigned short* w2p = w2e + (size_t)(wid * 64 + l16) * DFF + fc * FCH + lg * 8;
#pragma unroll
            for (int ks = 0; ks < 8; ++ks) {
                short8 B[4];
#pragma unroll
                for (int ct = 0; ct < 4; ++ct)
                    B[ct] = *(const short8*)(w2p + (size_t)ct * 16 * DFF + ks * 32);
#pragma unroll
                for (int rt = 0; rt < 4; ++rt) {
                    int row = rt * 16 + l16;
                    short8 A = *(const short8*)((const char*)Hs + row * 512 +
                                ((ks * 64 + lg * 16) ^ ((row & 7) << 4)));
#pragma unroll
                    for (int ct = 0; ct < 4; ++ct)
                        Yacc[rt][ct] = __builtin_amdgcn_mfma_f32_16x16x32_bf16(A, B[ct], Yacc[rt][ct], 0, 0, 0);
                }
            }
        }
        // ---- epilogue ----
#pragma unroll
        for (int rt = 0; rt < 4; ++rt)
#pragma unroll
        for (int r = 0; r < 4; ++r) {
            int row = rt * 16 + lg * 4 + r;
            int idx = t0 + row;
            if (idx < cnt) {
                int entry = sl[idx];
                float wgt = wl[idx];
                if constexpr (SLOT == 1) {
                    unsigned short* dst = ybuf + (size_t)entry * DM + wid * 64;
#pragma unroll
                    for (int ct = 0; ct < 4; ++ct)
                        dst[ct * 16 + l16] = f2bf(Yacc[rt][ct][r] * wgt);
                } else {
                    float* dst = out + (size_t)(entry >> 1) * DM + wid * 64;
#pragma unroll
                    for (int ct = 0; ct < 4; ++ct)
                        atomAddF(dst + ct * 16 + l16, Yacc[rt][ct][r] * wgt);
                }
            }
        }
        __syncthreads();   // Yacc stores done; safe to restage Xs next tile
    }
}

// ---------------- combine: out[t] = Ybuf[2t] + Ybuf[2t+1] ----------------
__global__ __launch_bounds__(256)
void combine_kernel(const unsigned short* __restrict__ ybuf, float* __restrict__ out) {
    int gid = blockIdx.x * 256 + threadIdx.x;   // T*64 threads, 8 cols each
    int t = gid >> 6, c8 = (gid & 63) * 8;
    const unsigned short* r0 = ybuf + ((size_t)t * 2) * DM + c8;
    short8 a = *(const short8*)r0;
    short8 b = *(const short8*)(r0 + DM);
    float* o = out + (size_t)t * DM + c8;
    f32x4 v0, v1;
    v0.x = bf2f((unsigned short)a[0]) + bf2f((unsigned short)b[0]);
    v0.y = bf2f((unsigned short)a[1]) + bf2f((unsigned short)b[1]);
    v0.z = bf2f((unsigned short)a[2]) + bf2f((unsigned short)b[2]);
    v0.w = bf2f((unsigned short)a[3]) + bf2f((unsigned short)b[3]);
    v1.x = bf2f((unsigned short)a[4]) + bf2f((unsigned short)b[4]);
    v1.y = bf2f((unsigned short)a[5]) + bf2f((unsigned short)b[5]);
    v1.z = bf2f((unsigned short)a[6]) + bf2f((unsigned short)b[6]);
    v1.w = bf2f((unsigned short)a[7]) + bf2f((unsigned short)b[7]);
    *(f32x4*)o = v0;
    *(f32x4*)(o + 4) = v1;
}

extern "C" void kernel_launch(void* const* d_in, const int* in_sizes, int n_in,
                              void* d_out, int out_size, void* d_ws, size_t ws_size,
                              hipStream_t stream) {
    const float* x  = (const float*)d_in[0];
    const float* gw = (const float*)d_in[1];
    const float* w1 = (const float*)d_in[2];
    const float* w2 = (const float*)d_in[3];
    float* out = (float*)d_out;
    char* ws = (char*)d_ws;

    const size_t W1N = (size_t)NE * DFF * DM;
    const size_t W2N = (size_t)NE * DM * DFF;
    unsigned short* w1b = (unsigned short*)ws;
    unsigned short* w2b = w1b + W1N;
    size_t off = (W1N + W2N) * 2;                       // 32 MiB
    int*   cursor   = (int*)(ws + off);   off += 256;
    int*   slotlist = (int*)(ws + off);   off += (size_t)NE * T_TOKENS * 4;
    float* wgtlist  = (float*)(ws + off); off += (size_t)NE * T_TOKENS * 4;
    float* entPart  = (float*)(ws + off); off += 8192;
    unsigned short* xbb = (unsigned short*)(ws + off); off += (size_t)T_TOKENS * DM * 2;
    size_t needB = off;
    unsigned short* ybuf = (unsigned short*)(ws + off); off += (size_t)T_TOKENS * 2 * DM * 2;
    size_t needA = off;

    int tier = (ws_size >= needA) ? 2 : ((ws_size >= needB) ? 1 : 0);

    hipMemsetAsync(cursor, 0, 64, stream);
    if (tier < 2) hipMemsetAsync(out, 0, RL_OFF * sizeof(float), stream);

    cvt_kernel<<<2048, 256, 0, stream>>>(w1, w1b, W1N / 4);
    cvt_kernel<<<2048, 256, 0, stream>>>(w2, w2b, W2N / 4);
    if (tier >= 1) cvt_kernel<<<2048, 256, 0, stream>>>(x, xbb, (size_t)T_TOKENS * DM / 4);

    router_kernel<<<T_TOKENS / 16, 1024, 0, stream>>>(x, gw, out, cursor, slotlist, wgtlist, entPart);
    ent_reduce<<<1, 1024, 0, stream>>>(entPart, out);

    if (tier == 2) {
        ffn_kernel<1, 1><<<NE * 64, 512, 0, stream>>>(x, xbb, w1b, w2b, cursor, slotlist, wgtlist, ybuf, out);
        combine_kernel<<<(T_TOKENS * DM / 8) / 256, 256, 0, stream>>>(ybuf, out);
    } else if (tier == 1) {
        ffn_kernel<1, 0><<<NE * 64, 512, 0, stream>>>(x, xbb, w1b, w2b, cursor, slotlist, wgtlist, nullptr, out);
    } else {
        ffn_kernel<0, 0><<<NE * 64, 512, 0, stream>>>(x, nullptr, w1b, w2b, cursor, slotlist, wgtlist, nullptr, out);
    }
}

// Round 4
// 515.125 us; speedup vs baseline: 2.1630x; 1.0236x over previous
//
#include <hip/hip_runtime.h>
#include <hip/hip_bf16.h>
#include <math.h>

#define T_TOKENS 16384
#define DM 512
#define DFF 2048
#define NE 8
#define TOKT 64
#define FCH 256
#define NFC (DFF / FCH)   // 8

// out layout: Y [16384*512] | router_logits [16384*8] | entropy [1]
#define RL_OFF  ((size_t)T_TOKENS * DM)
#define ENT_OFF (RL_OFF + (size_t)T_TOKENS * NE)

typedef __attribute__((ext_vector_type(8))) short short8;
typedef __attribute__((ext_vector_type(4))) float f32x4;

__device__ __forceinline__ unsigned short f2bf(float f) {
    union { float f; unsigned u; } v; v.f = f;
    unsigned r = v.u + 0x7FFFu + ((v.u >> 16) & 1u);   // RNE
    return (unsigned short)(r >> 16);
}
__device__ __forceinline__ float bf2f(unsigned short h) {
    union { unsigned u; float f; } v; v.u = ((unsigned)h) << 16; return v.f;
}
__device__ __forceinline__ void atomAddF(float* p, float v) {
    __hip_atomic_fetch_add(p, v, __ATOMIC_RELAXED, __HIP_MEMORY_SCOPE_AGENT);
}

// ---------------- fp32 -> bf16 conversion ----------------
__global__ void cvt_kernel(const float* __restrict__ src, unsigned short* __restrict__ dst, size_t n4) {
    for (size_t i = blockIdx.x * (size_t)blockDim.x + threadIdx.x; i < n4;
         i += (size_t)gridDim.x * blockDim.x) {
        f32x4 v = ((const f32x4*)src)[i];
        unsigned short b0 = f2bf(v.x), b1 = f2bf(v.y), b2 = f2bf(v.z), b3 = f2bf(v.w);
        ((unsigned long long*)dst)[i] =
            (unsigned long long)b0 | ((unsigned long long)b1 << 16) |
            ((unsigned long long)b2 << 32) | ((unsigned long long)b3 << 48);
    }
}

// ---------------- router ----------------
__global__ __launch_bounds__(1024)
void router_kernel(const float* __restrict__ x, const float* __restrict__ gw,
                   float* __restrict__ out, int* __restrict__ cursor,
                   int* __restrict__ slotlist, float* __restrict__ wgtlist,
                   float* __restrict__ entPartial) {
    __shared__ int   lcnt[NE];
    __shared__ int   lbase[NE];
    __shared__ float lent[16];
    __shared__ int   le[16][2];
    __shared__ int   lpos[16][2];
    __shared__ float lw[16][2];

    int tid = threadIdx.x;
    int wid = tid >> 6, lane = tid & 63;
    int t = blockIdx.x * 16 + wid;
    if (tid < NE) lcnt[tid] = 0;
    __syncthreads();

    const float* xr = x + (size_t)t * DM + lane * 8;
    f32x4 x0 = *(const f32x4*)xr;
    f32x4 x1 = *(const f32x4*)(xr + 4);

    float logit[NE];
#pragma unroll
    for (int e = 0; e < NE; ++e) {
        const float* g = gw + e * DM + lane * 8;
        f32x4 g0 = *(const f32x4*)g;
        f32x4 g1 = *(const f32x4*)(g + 4);
        float p = x0.x*g0.x + x0.y*g0.y + x0.z*g0.z + x0.w*g0.w
                + x1.x*g1.x + x1.y*g1.y + x1.z*g1.z + x1.w*g1.w;
#pragma unroll
        for (int off = 32; off > 0; off >>= 1) p += __shfl_xor(p, off);
        logit[e] = p;
    }
    float m = logit[0];
#pragma unroll
    for (int e = 1; e < NE; ++e) m = fmaxf(m, logit[e]);
    float pr[NE]; float s = 0.f;
#pragma unroll
    for (int e = 0; e < NE; ++e) { pr[e] = expf(logit[e] - m); s += pr[e]; }
    float inv = 1.f / s;
    float ent = 0.f;
#pragma unroll
    for (int e = 0; e < NE; ++e) { pr[e] *= inv; ent -= pr[e] * logf(fmaxf(pr[e], 1e-6f)); }
    float p0 = -1.f, p1 = -1.f; int e0 = 0, e1 = 0;
#pragma unroll
    for (int e = 0; e < NE; ++e) {
        float p = pr[e];
        if (p > p0)      { p1 = p0; e1 = e0; p0 = p; e0 = e; }
        else if (p > p1) { p1 = p;  e1 = e; }
    }
    float wsum = p0 + p1;

    if (lane == 0) {
        lent[wid] = ent;
        le[wid][0] = e0; le[wid][1] = e1;
        lw[wid][0] = p0 / wsum; lw[wid][1] = p1 / wsum;
        lpos[wid][0] = atomicAdd(&lcnt[e0], 1);
        lpos[wid][1] = atomicAdd(&lcnt[e1], 1);
    }
    float myLogit = 0.f;
#pragma unroll
    for (int e = 0; e < NE; ++e) if (lane == e) myLogit = logit[e];
    if (lane < NE) out[RL_OFF + (size_t)t * NE + lane] = myLogit;

    __syncthreads();
    if (tid < NE) lbase[tid] = atomicAdd(cursor + tid, lcnt[tid]);
    __syncthreads();
    if (tid < 16) {
        int a0 = le[tid][0], a1 = le[tid][1];
        int tt = blockIdx.x * 16 + tid;
        int q0 = lbase[a0] + lpos[tid][0];
        int q1 = lbase[a1] + lpos[tid][1];
        slotlist[a0 * T_TOKENS + q0] = tt * 2;     wgtlist[a0 * T_TOKENS + q0] = lw[tid][0];
        slotlist[a1 * T_TOKENS + q1] = tt * 2 + 1; wgtlist[a1 * T_TOKENS + q1] = lw[tid][1];
    }
    if (tid == 0) {
        float sum = 0.f;
#pragma unroll
        for (int w = 0; w < 16; ++w) sum += lent[w];
        entPartial[blockIdx.x] = sum;
    }
}

__global__ void ent_reduce(const float* __restrict__ part, float* __restrict__ out) {
    __shared__ float s[16];
    int tid = threadIdx.x;
    float v = part[tid];
#pragma unroll
    for (int off = 32; off > 0; off >>= 1) v += __shfl_xor(v, off);
    if ((tid & 63) == 0) s[tid >> 6] = v;
    __syncthreads();
    if (tid == 0) {
        float tot = 0.f;
#pragma unroll
        for (int w = 0; w < 16; ++w) tot += s[w];
        out[ENT_OFF] = tot * (1.0f / T_TOKENS);
    }
}

// ---------------- grouped fused FFN ----------------
// 64-token tile x 1 expert per block, 512 threads = 8 waves, 96.5 KB LDS, 1 block/CU.
// Stage1 SWAPPED: Hacc[f][token] = mfma(W1frag, Xfrag) -> GELU written as b64 to Hs.
// Deep register prefetch: W1 depth-3 ring, W2 depth-2 ring, issued across barriers.
// Barriers: stage1 -> bar -> GELU(write Hs) -> bar -> stage2 (reads Hs). Stage1 touches
// no Hs, so it overlaps the previous stage2's readers before the barrier.
template <int XB, int SLOT>
__global__ __launch_bounds__(512, 2)
void ffn_kernel(const float* __restrict__ x, const unsigned short* __restrict__ xb,
                const unsigned short* __restrict__ w1b, const unsigned short* __restrict__ w2b,
                const int* __restrict__ cursor, const int* __restrict__ slotlist,
                const float* __restrict__ wgtlist,
                unsigned short* __restrict__ ybuf, float* __restrict__ out) {
    __shared__ char XsB[TOKT * DM * 2];    // 64 KB, row stride 1024 B, XOR swizzled
    __shared__ char HsB[TOKT * FCH * 2];   // 32 KB, row stride 512 B, XOR swizzled
    __shared__ int   tIdx[TOKT];
    __shared__ float tW[TOKT];

    int e   = blockIdx.x & 7;              // expert == XCD for L2 pinning
    int cnt = cursor[e];
    int tid = threadIdx.x;
    int wid = tid >> 6, lane = tid & 63;
    int l16 = lane & 15, lg = lane >> 4;
    int swz = (l16 & 7) << 4;

    const unsigned short* w1e = w1b + (size_t)e * DFF * DM;
    const unsigned short* w2e = w2b + (size_t)e * DM * DFF;
    const int*   sl = slotlist + e * T_TOKENS;
    const float* wl = wgtlist  + e * T_TOKENS;

    int step = (gridDim.x >> 3) * TOKT;
#pragma unroll 1
    for (int t0 = (blockIdx.x >> 3) * TOKT; t0 < cnt; t0 += step) {
        if (tid < TOKT) {
            int i = t0 + tid;
            int src = (i < cnt) ? i : t0;
            tIdx[tid] = sl[src] >> 1;
            tW[tid]   = (i < cnt) ? wl[i] : 0.f;
        }
        // ---- stage X once: 4096 x 16B units, 8 per thread ----
#pragma unroll
        for (int it = 0; it < 8; ++it) {
            int u = tid + it * 512;
            int row = u >> 6, c16 = u & 63;
            int idx = t0 + row;
            int sidx = (idx < cnt) ? idx : t0;
            int t = sl[sidx] >> 1;
            short8 v;
            if constexpr (XB == 1) {
                v = *(const short8*)(xb + (size_t)t * DM + c16 * 8);
            } else {
                const float* src = x + (size_t)t * DM + c16 * 8;
                f32x4 a = *(const f32x4*)src, b = *(const f32x4*)(src + 4);
                v[0]=(short)f2bf(a.x); v[1]=(short)f2bf(a.y); v[2]=(short)f2bf(a.z); v[3]=(short)f2bf(a.w);
                v[4]=(short)f2bf(b.x); v[5]=(short)f2bf(b.y); v[6]=(short)f2bf(b.z); v[7]=(short)f2bf(b.w);
            }
            *(short8*)(XsB + row * 1024 + ((c16 << 4) ^ ((row & 7) << 4))) = v;
        }
        __syncthreads();

        f32x4 Yacc[4][4] = {};   // [tt][gt]
        const unsigned short* w1base = w1e + (size_t)(wid * 32 + l16) * DM + lg * 8;
        const unsigned short* w2base = w2e + (size_t)(wid * 64 + l16) * DFF + lg * 8;

        // preload fc=0 stage1 W1 ring (depth 3, 2 f-tiles per slot)
        short8 Ap[3][2];
#pragma unroll
        for (int k = 0; k < 3; ++k) {
            Ap[k][0] = *(const short8*)(w1base + k * 32);
            Ap[k][1] = *(const short8*)(w1base + 16 * DM + k * 32);
        }

#pragma unroll 1
        for (int fc = 0; fc < NFC; ++fc) {
            const unsigned short* w1f = w1base + (size_t)fc * FCH * DM;
            f32x4 Hacc[2][4] = {};   // [ft][tt], D[f][token]
            // ---- stage1: 16 ks, swapped mfma(W1, X) ----
#pragma unroll
            for (int ks = 0; ks < 16; ++ks) {
                short8 a0 = Ap[ks % 3][0], a1 = Ap[ks % 3][1];
                if (ks < 13) {
                    Ap[ks % 3][0] = *(const short8*)(w1f + (ks + 3) * 32);
                    Ap[ks % 3][1] = *(const short8*)(w1f + 16 * DM + (ks + 3) * 32);
                }
#pragma unroll
                for (int tt = 0; tt < 4; ++tt) {
                    short8 xf = *(const short8*)(XsB + (tt * 16 + l16) * 1024 +
                                                 ((ks * 64 + lg * 16) ^ swz));
                    Hacc[0][tt] = __builtin_amdgcn_mfma_f32_16x16x32_bf16(a0, xf, Hacc[0][tt], 0, 0, 0);
                    Hacc[1][tt] = __builtin_amdgcn_mfma_f32_16x16x32_bf16(a1, xf, Hacc[1][tt], 0, 0, 0);
                }
            }
            // next-fc W1 preload: in flight across GELU + stage2 (~800+ cyc cover)
            if (fc + 1 < NFC) {
                const unsigned short* w1n = w1base + (size_t)(fc + 1) * FCH * DM;
#pragma unroll
                for (int k = 0; k < 3; ++k) {
                    Ap[k][0] = *(const short8*)(w1n + k * 32);
                    Ap[k][1] = *(const short8*)(w1n + 16 * DM + k * 32);
                }
            }
            // stage2 W2 preload (ks 0,1) — global only, safe before barrier
            const unsigned short* w2f = w2base + fc * FCH;
            short8 Bp[2][4];
#pragma unroll
            for (int k = 0; k < 2; ++k)
#pragma unroll
                for (int gt = 0; gt < 4; ++gt)
                    Bp[k][gt] = *(const short8*)(w2f + (size_t)gt * 16 * DFF + k * 32);

            __syncthreads();   // all waves finished reading Hs (prev fc stage2)
            // ---- GELU -> Hs, vectorized b64 (4 consecutive f per lane) ----
#pragma unroll
            for (int ft = 0; ft < 2; ++ft)
#pragma unroll
            for (int tt = 0; tt < 4; ++tt) {
                f32x4 h = Hacc[ft][tt];
                unsigned long long pk = 0;
#pragma unroll
                for (int r = 0; r < 4; ++r) {
                    float g = 0.5f * h[r] * (1.0f + erff(h[r] * 0.70710678118f));
                    pk |= (unsigned long long)f2bf(g) << (r * 16);
                }
                int token = tt * 16 + l16;
                int f2 = wid * 64 + ft * 32 + lg * 8;   // f_local byte offset
                *(unsigned long long*)(HsB + token * 512 + (f2 ^ swz)) = pk;
            }
            __syncthreads();
            // ---- stage2: Y[token][g] += H * W2^T, 8 ks ----
#pragma unroll
            for (int ks = 0; ks < 8; ++ks) {
                short8 b0 = Bp[ks & 1][0], b1 = Bp[ks & 1][1];
                short8 b2 = Bp[ks & 1][2], b3 = Bp[ks & 1][3];
                if (ks < 6) {
#pragma unroll
                    for (int gt = 0; gt < 4; ++gt)
                        Bp[ks & 1][gt] = *(const short8*)(w2f + (size_t)gt * 16 * DFF + (ks + 2) * 32);
                }
#pragma unroll
                for (int tt = 0; tt < 4; ++tt) {
                    short8 af = *(const short8*)(HsB + (tt * 16 + l16) * 512 +
                                                 ((ks * 64 + lg * 16) ^ swz));
                    Yacc[tt][0] = __builtin_amdgcn_mfma_f32_16x16x32_bf16(af, b0, Yacc[tt][0], 0, 0, 0);
                    Yacc[tt][1] = __builtin_amdgcn_mfma_f32_16x16x32_bf16(af, b1, Yacc[tt][1], 0, 0, 0);
                    Yacc[tt][2] = __builtin_amdgcn_mfma_f32_16x16x32_bf16(af, b2, Yacc[tt][2], 0, 0, 0);
                    Yacc[tt][3] = __builtin_amdgcn_mfma_f32_16x16x32_bf16(af, b3, Yacc[tt][3], 0, 0, 0);
                }
            }
        }
        // ---- epilogue: scale + store ----
#pragma unroll
        for (int tt = 0; tt < 4; ++tt)
#pragma unroll
        for (int r = 0; r < 4; ++r) {
            int row = tt * 16 + lg * 4 + r;
            int idx = t0 + row;
            if (idx < cnt) {
                int entry = sl[idx];
                float wgt = tW[row];
                if constexpr (SLOT == 1) {
                    unsigned short* dst = ybuf + (size_t)entry * DM + wid * 64;
#pragma unroll
                    for (int gt = 0; gt < 4; ++gt)
                        dst[gt * 16 + l16] = f2bf(Yacc[tt][gt][r] * wgt);
                } else {
                    float* dst = out + (size_t)(entry >> 1) * DM + wid * 64;
#pragma unroll
                    for (int gt = 0; gt < 4; ++gt)
                        atomAddF(dst + gt * 16 + l16, Yacc[tt][gt][r] * wgt);
                }
            }
        }
        __syncthreads();   // stores done; safe to restage Xs/tIdx next tile
    }
}

// ---------------- combine: out[t] = Ybuf[2t] + Ybuf[2t+1] ----------------
__global__ __launch_bounds__(256)
void combine_kernel(const unsigned short* __restrict__ ybuf, float* __restrict__ out) {
    int gid = blockIdx.x * 256 + threadIdx.x;
    int t = gid >> 6, c8 = (gid & 63) * 8;
    const unsigned short* r0 = ybuf + ((size_t)t * 2) * DM + c8;
    short8 a = *(const short8*)r0;
    short8 b = *(const short8*)(r0 + DM);
    float* o = out + (size_t)t * DM + c8;
    f32x4 v0, v1;
    v0.x = bf2f((unsigned short)a[0]) + bf2f((unsigned short)b[0]);
    v0.y = bf2f((unsigned short)a[1]) + bf2f((unsigned short)b[1]);
    v0.z = bf2f((unsigned short)a[2]) + bf2f((unsigned short)b[2]);
    v0.w = bf2f((unsigned short)a[3]) + bf2f((unsigned short)b[3]);
    v1.x = bf2f((unsigned short)a[4]) + bf2f((unsigned short)b[4]);
    v1.y = bf2f((unsigned short)a[5]) + bf2f((unsigned short)b[5]);
    v1.z = bf2f((unsigned short)a[6]) + bf2f((unsigned short)b[6]);
    v1.w = bf2f((unsigned short)a[7]) + bf2f((unsigned short)b[7]);
    *(f32x4*)o = v0;
    *(f32x4*)(o + 4) = v1;
}

extern "C" void kernel_launch(void* const* d_in, const int* in_sizes, int n_in,
                              void* d_out, int out_size, void* d_ws, size_t ws_size,
                              hipStream_t stream) {
    const float* x  = (const float*)d_in[0];
    const float* gw = (const float*)d_in[1];
    const float* w1 = (const float*)d_in[2];
    const float* w2 = (const float*)d_in[3];
    float* out = (float*)d_out;
    char* ws = (char*)d_ws;

    const size_t W1N = (size_t)NE * DFF * DM;
    const size_t W2N = (size_t)NE * DM * DFF;
    unsigned short* w1b = (unsigned short*)ws;
    unsigned short* w2b = w1b + W1N;
    size_t off = (W1N + W2N) * 2;                       // 32 MiB
    int*   cursor   = (int*)(ws + off);   off += 256;
    int*   slotlist = (int*)(ws + off);   off += (size_t)NE * T_TOKENS * 4;
    float* wgtlist  = (float*)(ws + off); off += (size_t)NE * T_TOKENS * 4;
    float* entPart  = (float*)(ws + off); off += 8192;
    unsigned short* xbb = (unsigned short*)(ws + off); off += (size_t)T_TOKENS * DM * 2;
    size_t needB = off;
    unsigned short* ybuf = (unsigned short*)(ws + off); off += (size_t)T_TOKENS * 2 * DM * 2;
    size_t needA = off;

    int tier = (ws_size >= needA) ? 2 : ((ws_size >= needB) ? 1 : 0);

    hipMemsetAsync(cursor, 0, 64, stream);
    if (tier < 2) hipMemsetAsync(out, 0, RL_OFF * sizeof(float), stream);

    cvt_kernel<<<2048, 256, 0, stream>>>(w1, w1b, W1N / 4);
    cvt_kernel<<<2048, 256, 0, stream>>>(w2, w2b, W2N / 4);
    if (tier >= 1) cvt_kernel<<<2048, 256, 0, stream>>>(x, xbb, (size_t)T_TOKENS * DM / 4);

    router_kernel<<<T_TOKENS / 16, 1024, 0, stream>>>(x, gw, out, cursor, slotlist, wgtlist, entPart);
    ent_reduce<<<1, 1024, 0, stream>>>(entPart, out);

    if (tier == 2) {
        ffn_kernel<1, 1><<<NE * 64, 512, 0, stream>>>(x, xbb, w1b, w2b, cursor, slotlist, wgtlist, ybuf, out);
        combine_kernel<<<(T_TOKENS * DM / 8) / 256, 256, 0, stream>>>(ybuf, out);
    } else if (tier == 1) {
        ffn_kernel<1, 0><<<NE * 64, 512, 0, stream>>>(x, xbb, w1b, w2b, cursor, slotlist, wgtlist, nullptr, out);
    } else {
        ffn_kernel<0, 0><<<NE * 64, 512, 0, stream>>>(x, nullptr, w1b, w2b, cursor, slotlist, wgtlist, nullptr, out);
    }
}